// Round 4
// baseline (365.859 us; speedup 1.0000x reference)
//
#include <hip/hip_runtime.h>

#define NN 100
#define CC 256
#define NKK 103
#define LSA 72    // staging row stride: 64 + 8 bf16
#define LDP 136   // PW row stride: 128 + 8 bf16

typedef __bf16 bf16;
typedef __bf16 bf16x4 __attribute__((ext_vector_type(4)));
typedef __bf16 bf16x8 __attribute__((ext_vector_type(8)));
typedef float f32x4 __attribute__((ext_vector_type(4)));

__global__ __launch_bounds__(512, 6)
void dysepconv_fused(const float* __restrict__ query,
                     const float* __restrict__ value,
                     const float* __restrict__ W,
                     const float* __restrict__ bwl,
                     const float* __restrict__ gamma,
                     const float* __restrict__ beta,
                     float* __restrict__ out)
{
    // LDS: 30528 (stage, aliased by PW 17408) + 1200 + 4096 + 512 = 36336 B
    __shared__ __align__(16) bf16 SREG[100 * LSA + 112 * LSA];
    __shared__ float DW[NN][3];
    __shared__ float RP[8][64][2];
    __shared__ float RS[64][2];

    bf16* Abuf = SREG;                // [100][LSA]  query chunk, bf16
    bf16* Wbuf = SREG + 100 * LSA;    // [112][LSA]  W^T chunk, bf16 (rows >=103 garbage, masked)
    bf16* PW   = SREG;                // [64][LDP]   aliases staging after phase A

    const int t    = threadIdx.x;
    const int w    = t >> 6;          // wave 0..7
    const int lane = t & 63;
    const int ln16 = lane & 15;
    const int g    = lane >> 4;
    const int hi8  = g * 8;
    const int bb   = blockIdx.x;
    const int b    = bb >> 1;
    const int n0   = (bb & 1) * 50;   // this block owns out rows n0..n0+49

    const float* qb = query + (size_t)b * NN * CC;
    const float* vb = value + (size_t)b * NN * CC;

    // ---------------- Phase A: dy = q @ W + b (staged, chunked K=64) ----------------
    f32x4 acc1[4];
    #pragma unroll
    for (int I = 0; I < 4; ++I) acc1[I] = (f32x4){0.f, 0.f, 0.f, 0.f};

    const int  dm    = t / 3, dk = t - dm * 3;   // dw work item (t<300)
    const bool do_dw = (t < 300);
    float dwacc = 0.f;

    for (int kc = 0; kc < 4; ++kc) {
        const int k0 = kc * 64;
        __syncthreads();   // prior chunk's LDS reads complete

        // batched independent loads: 4x f32x4 (query, 1600 items) + 13x f32 (W), one drain
        f32x4 qv[4];
        #pragma unroll
        for (int p = 0; p < 4; ++p) {
            int idx = p * 512 + t;                      // covers 0..2047, need <1600
            if (idx < 1600) {
                int r = idx >> 4, j = (idx & 15) << 2;
                qv[p] = *(const f32x4*)(qb + r * CC + k0 + j);
            }
        }
        float wv[13];
        #pragma unroll
        for (int p = 0; p < 13; ++p) {
            int idx = p * 512 + t;                      // < 6656, need <6592
            if (idx < 64 * NKK) {
                int kk = idx / NKK, ka = idx - kk * NKK;
                wv[p] = W[(size_t)(k0 + kk) * NKK + ka];
            }
        }
        #pragma unroll
        for (int p = 0; p < 4; ++p) {
            int idx = p * 512 + t;
            if (idx < 1600) {
                int r = idx >> 4, j = (idx & 15) << 2;
                bf16x4 s;
                #pragma unroll
                for (int i = 0; i < 4; ++i) s[i] = (bf16)qv[p][i];
                *(bf16x4*)&Abuf[r * LSA + j] = s;
            }
        }
        #pragma unroll
        for (int p = 0; p < 13; ++p) {
            int idx = p * 512 + t;
            if (idx < 64 * NKK) {
                int kk = idx / NKK, ka = idx - kk * NKK;
                Wbuf[ka * LSA + kk] = (bf16)wv[p];      // transposed scatter
            }
        }
        __syncthreads();

        // MFMA: wave w<7 owns N-tile J=w, M-tiles I=0..3 (rows n0..n0+63, clamped)
        if (w < 7) {
            #pragma unroll
            for (int s = 0; s < 2; ++s) {
                bf16x8 bv = *(const bf16x8*)&Wbuf[(w * 16 + ln16) * LSA + s * 32 + hi8];
                #pragma unroll
                for (int I = 0; I < 4; ++I) {
                    int row = n0 + I * 16 + ln16;
                    row = row < NN ? row : NN - 1;      // clamped rows -> discarded outputs
                    bf16x8 av = *(const bf16x8*)&Abuf[row * LSA + s * 32 + hi8];
                    acc1[I] = __builtin_amdgcn_mfma_f32_16x16x32_bf16(av, bv, acc1[I], 0, 0, 0);
                }
            }
        }
        // dw partials: dy[:, 0:3] via LDS dot (full M needed, n-split can't cover it with MFMA)
        if (do_dw) {
            #pragma unroll
            for (int jb = 0; jb < 8; ++jb) {
                bf16x8 a = *(const bf16x8*)&Abuf[dm * LSA + jb * 8];
                bf16x8 c = *(const bf16x8*)&Wbuf[dk * LSA + jb * 8];
                #pragma unroll
                for (int i = 0; i < 8; ++i) dwacc += (float)a[i] * (float)c[i];
            }
        }
    }
    __syncthreads();   // all staging reads done -> PW may alias

    // epilogue A: zero PW pad cols (k-dim, must be exact 0), write pw/dw
    for (int i = t; i < 64 * 28; i += 512) {
        int r = i / 28, m = 100 + (i - (i / 28) * 28);
        PW[r * LDP + m] = (bf16)0.f;
    }
    if (w < 7) {
        const int kap = w * 16 + ln16;
        const float bw = (kap < NKK) ? bwl[kap] : 0.f;
        #pragma unroll
        for (int I = 0; I < 4; ++I) {
            #pragma unroll
            for (int r = 0; r < 4; ++r) {
                int nloc = I * 16 + g * 4 + r;
                if (kap >= 3 && kap < NKK)
                    PW[nloc * LDP + (kap - 3)] = (bf16)(acc1[I][r] + bw);
            }
        }
    }
    if (do_dw) DW[dm][dk] = dwacc + bwl[dk];
    __syncthreads();

    // ---------------- Phase B/C: conv (register B-layout) + GEMM2 ----------------
    f32x4 acc2[2][4];
    #pragma unroll
    for (int st = 0; st < 2; ++st)
        #pragma unroll
        for (int I = 0; I < 4; ++I) acc2[st][I] = (f32x4){0.f, 0.f, 0.f, 0.f};

    const int cbase = w * 16 + ln16;   // st0: cbase, st1: cbase+128
    #pragma unroll
    for (int ks = 0; ks < 4; ++ks) {
        bf16x8 dv0, dv1;
        #pragma unroll
        for (int j = 0; j < 8; ++j) {
            int  m  = ks * 32 + hi8 + j;
            bool mv = (m < NN);
            int  mc = mv ? m : NN - 1;
            const float* vr = vb + m * CC;
            float w0 = DW[mc][0], w1 = DW[mc][1], w2 = DW[mc][2];
            float x0 = mv ? vr[cbase]       : 0.f;
            float y0 = mv ? vr[cbase + 128] : 0.f;
            float xm = __shfl(x0, (lane - 1) & 63), xp = __shfl(x0, (lane + 1) & 63);
            float ym = __shfl(y0, (lane - 1) & 63), yp = __shfl(y0, (lane + 1) & 63);
            if (ln16 == 0) {
                xm = (mv && cbase > 0) ? vr[cbase - 1] : 0.f;
                ym = mv ? vr[cbase + 127] : 0.f;
            }
            if (ln16 == 15) {
                xp = mv ? vr[cbase + 1] : 0.f;                       // cbase<=127 -> valid
                yp = (mv && cbase + 129 < CC) ? vr[cbase + 129] : 0.f;
            }
            float d0 = w0 * xm + w1 * x0 + w2 * xp;
            float d1 = w0 * ym + w1 * y0 + w2 * yp;
            dv0[j] = (bf16)(mv ? fmaxf(d0, 0.f) : 0.f);
            dv1[j] = (bf16)(mv ? fmaxf(d1, 0.f) : 0.f);
        }
        #pragma unroll
        for (int I = 0; I < 4; ++I) {
            bf16x8 af = *(const bf16x8*)&PW[(I * 16 + ln16) * LDP + ks * 32 + hi8];
            acc2[0][I] = __builtin_amdgcn_mfma_f32_16x16x32_bf16(af, dv0, acc2[0][I], 0, 0, 0);
            acc2[1][I] = __builtin_amdgcn_mfma_f32_16x16x32_bf16(af, dv1, acc2[1][I], 0, 0, 0);
        }
    }

    // ---------------- Phase D: LayerNorm + store ----------------
    #pragma unroll
    for (int I = 0; I < 4; ++I) {
        #pragma unroll
        for (int r = 0; r < 4; ++r) {
            float a = acc2[0][I][r], e = acc2[1][I][r];
            float s1 = a + e, s2 = a * a + e * e;
            #pragma unroll
            for (int mk = 1; mk < 16; mk <<= 1) {
                s1 += __shfl_xor(s1, mk);
                s2 += __shfl_xor(s2, mk);
            }
            if (ln16 == 0) {
                int nloc = I * 16 + g * 4 + r;
                RP[w][nloc][0] = s1;
                RP[w][nloc][1] = s2;
            }
        }
    }
    __syncthreads();
    if (t < 64) {
        float S1 = 0.f, S2 = 0.f;
        #pragma unroll
        for (int wi = 0; wi < 8; ++wi) { S1 += RP[wi][t][0]; S2 += RP[wi][t][1]; }
        float mu  = S1 * (1.f / 256.f);
        float var = S2 * (1.f / 256.f) - mu * mu;
        RS[t][0] = mu;
        RS[t][1] = rsqrtf(fmaxf(var, 0.f) + 1e-5f);
    }
    __syncthreads();

    const float gm0 = gamma[cbase], gm1 = gamma[cbase + 128];
    const float bt0 = beta[cbase],  bt1 = beta[cbase + 128];
    float* ob = out + (size_t)b * NN * CC + (size_t)n0 * CC;
    #pragma unroll
    for (int I = 0; I < 4; ++I) {
        #pragma unroll
        for (int r = 0; r < 4; ++r) {
            int nloc = I * 16 + g * 4 + r;
            if (nloc < 50) {
                float mu = RS[nloc][0], rs = RS[nloc][1];
                ob[nloc * CC + cbase]       = (acc2[0][I][r] - mu) * rs * gm0 + bt0;
                ob[nloc * CC + cbase + 128] = (acc2[1][I][r] - mu) * rs * gm1 + bt1;
            }
        }
    }
}

extern "C" void kernel_launch(void* const* d_in, const int* in_sizes, int n_in,
                              void* d_out, int out_size, void* d_ws, size_t ws_size,
                              hipStream_t stream) {
    const float* query = (const float*)d_in[0];
    const float* value = (const float*)d_in[1];
    const float* W     = (const float*)d_in[2];
    const float* bwl   = (const float*)d_in[3];
    const float* gamma = (const float*)d_in[4];
    const float* beta  = (const float*)d_in[5];
    dysepconv_fused<<<dim3(1024), dim3(512), 0, stream>>>(query, value, W, bwl, gamma, beta, (float*)d_out);
}

// Round 5
// 191.124 us; speedup vs baseline: 1.9143x; 1.9143x over previous
//
#include <hip/hip_runtime.h>

#define NN 100
#define CC 256
#define NKK 103
#define LSA 72     // Abuf/Wbuf stride (bf16): 144 B rows, 16B-aligned frags, bank-staggered
#define LDPW 136   // PW stride (bf16): 272 B rows, 16B-aligned frags
#define OTS 260    // out-transpose stride (f32): 1040 B rows, 16B-aligned

typedef __bf16 bf16;
typedef __bf16 bf16x4 __attribute__((ext_vector_type(4)));
typedef __bf16 bf16x8 __attribute__((ext_vector_type(8)));
typedef float f32x4 __attribute__((ext_vector_type(4)));

__global__ __launch_bounds__(512, 4)
void dysepconv_fused(const float* __restrict__ query,
                     const float* __restrict__ value,
                     const float* __restrict__ W,
                     const float* __restrict__ bwl,
                     const float* __restrict__ gamma,
                     const float* __restrict__ beta,
                     float* __restrict__ out)
{
    // LDS: PW 27200 + R 29232 + DW 1200 + RP 6400 + RS 800 = 64832 B (<= 64 KB, 2 blocks/CU)
    __shared__ __align__(16) bf16 PW[NN * LDPW];                  // pw [n][m], cols 100..127 zeroed
    __shared__ __align__(16) bf16 R[100 * LSA + NKK * LSA];       // A: Abuf+Wbuf | D: OT (16x260 f32)
    __shared__ float DW[NN][3];
    __shared__ float RP[8][NN][2];
    __shared__ float RS[NN][2];

    bf16*  Abuf = R;                  // [100][LSA]
    bf16*  Wbuf = R + 100 * LSA;      // [103][LSA]  W^T chunk
    float* OT   = (float*)R;          // [16][OTS]   phase-D transpose tile

    const int t    = threadIdx.x;
    const int w    = t >> 6;          // wave 0..7
    const int lane = t & 63;
    const int ln16 = lane & 15;
    const int g    = lane >> 4;
    const int hi8  = g * 8;
    const int b    = blockIdx.x;

    const float* qb = query + (size_t)b * NN * CC;
    const float* vb = value + (size_t)b * NN * CC;

    // ---------------- Phase A: dy = q @ W + bias ----------------
    f32x4 acc1[7];
    #pragma unroll
    for (int I = 0; I < 7; ++I) acc1[I] = (f32x4){0.f, 0.f, 0.f, 0.f};

    for (int kc = 0; kc < 4; ++kc) {
        const int k0 = kc * 64;
        __syncthreads();                       // prior chunk's LDS reads complete
        {   // query chunk: 1600 f32x4 items, coalesced
            f32x4 qv[4];
            #pragma unroll
            for (int p = 0; p < 4; ++p) {
                int idx = p * 512 + t;
                if (idx < 1600) {
                    int r = idx >> 4, j = (idx & 15) << 2;
                    qv[p] = *(const f32x4*)(qb + r * CC + k0 + j);
                }
            }
            #pragma unroll
            for (int p = 0; p < 4; ++p) {
                int idx = p * 512 + t;
                if (idx < 1600) {
                    int r = idx >> 4, j = (idx & 15) << 2;
                    bf16x4 s;
                    #pragma unroll
                    for (int i = 0; i < 4; ++i) s[i] = (bf16)qv[p][i];
                    *(bf16x4*)&Abuf[r * LSA + j] = s;
                }
            }
        }
        {   // W chunk: 64x103 scalar items, coalesced load, transposed scatter
            float wv[13];
            #pragma unroll
            for (int p = 0; p < 13; ++p) {
                int idx = p * 512 + t;
                if (idx < 64 * NKK) {
                    int kk = idx / NKK, ka = idx - kk * NKK;
                    wv[p] = W[(size_t)(k0 + kk) * NKK + ka];
                }
            }
            #pragma unroll
            for (int p = 0; p < 13; ++p) {
                int idx = p * 512 + t;
                if (idx < 64 * NKK) {
                    int kk = idx / NKK, ka = idx - kk * NKK;
                    Wbuf[ka * LSA + kk] = (bf16)wv[p];
                }
            }
        }
        __syncthreads();

        if (w < 7) {
            const int rB = (w * 16 + ln16 < NKK) ? (w * 16 + ln16) : (NKK - 1); // clamp: cols>=103 discarded
            #pragma unroll
            for (int s = 0; s < 2; ++s) {
                bf16x8 bv = *(const bf16x8*)&Wbuf[rB * LSA + s * 32 + hi8];
                #pragma unroll
                for (int I = 0; I < 7; ++I) {
                    int row = I * 16 + ln16;
                    row = (row < NN) ? row : (NN - 1);   // clamp: rows>=100 discarded
                    bf16x8 av = *(const bf16x8*)&Abuf[row * LSA + s * 32 + hi8];
                    acc1[I] = __builtin_amdgcn_mfma_f32_16x16x32_bf16(av, bv, acc1[I], 0, 0, 0);
                }
            }
        }
    }
    __syncthreads();   // last chunk's Abuf/Wbuf reads done (R reused by OT much later)

    // epilogue A: zero PW k-pad cols (must be exact 0), write pw (bf16) / dw (fp32)
    for (int i = t; i < NN * 28; i += 512) {
        int r = i / 28, m = 100 + (i - (i / 28) * 28);
        PW[r * LDPW + m] = (bf16)0.f;
    }
    if (w < 7) {
        const int kap = w * 16 + ln16;
        const float bw = (kap < NKK) ? bwl[kap] : 0.f;
        #pragma unroll
        for (int I = 0; I < 7; ++I) {
            #pragma unroll
            for (int r = 0; r < 4; ++r) {
                int n = I * 16 + g * 4 + r;
                if (n < NN && kap < NKK) {
                    float v = acc1[I][r] + bw;
                    if (kap < 3) DW[n][kap] = v;
                    else         PW[n * LDPW + (kap - 3)] = (bf16)v;
                }
            }
        }
    }
    __syncthreads();   // PW/DW visible

    // ---------------- Phase B/C: conv (register B-layout, batched loads) + GEMM2 ----------------
    f32x4 acc2[2][7];
    #pragma unroll
    for (int st = 0; st < 2; ++st)
        #pragma unroll
        for (int I = 0; I < 7; ++I) acc2[st][I] = (f32x4){0.f, 0.f, 0.f, 0.f};

    const int cb = w * 16 + ln16;    // st0: cb (0..127), st1: cb+128
    #pragma unroll
    for (int ks = 0; ks < 4; ++ks) {
        // batch all 16 value loads for this ks, one drain
        float xv[8], yv[8];
        #pragma unroll
        for (int j = 0; j < 8; ++j) {
            int m = ks * 32 + hi8 + j;
            bool mv = (m < NN);
            const float* vr = vb + m * CC;
            xv[j] = mv ? vr[cb]       : 0.f;
            yv[j] = mv ? vr[cb + 128] : 0.f;
        }
        bf16x8 dv0, dv1;
        #pragma unroll
        for (int j = 0; j < 8; ++j) {
            int  m  = ks * 32 + hi8 + j;
            bool mv = (m < NN);
            int  mc = mv ? m : (NN - 1);
            float w0 = DW[mc][0], w1 = DW[mc][1], w2 = DW[mc][2];
            float x0 = xv[j], y0 = yv[j];
            float xm = __shfl(x0, (lane - 1) & 63), xp = __shfl(x0, (lane + 1) & 63);
            float ym = __shfl(y0, (lane - 1) & 63), yp = __shfl(y0, (lane + 1) & 63);
            if (ln16 == 0) {
                xm = (mv && cb > 0) ? vb[m * CC + cb - 1] : 0.f;
                ym = mv ? vb[m * CC + cb + 127] : 0.f;
            }
            if (ln16 == 15) {
                xp = mv ? vb[m * CC + cb + 1] : 0.f;
                yp = (mv && cb + 129 < CC) ? vb[m * CC + cb + 129] : 0.f;
            }
            float d0 = w0 * xm + w1 * x0 + w2 * xp;
            float d1 = w0 * ym + w1 * y0 + w2 * yp;
            dv0[j] = (bf16)(mv ? fmaxf(d0, 0.f) : 0.f);
            dv1[j] = (bf16)(mv ? fmaxf(d1, 0.f) : 0.f);
        }
        #pragma unroll
        for (int I = 0; I < 7; ++I) {
            int row = I * 16 + ln16;
            row = (row < NN) ? row : (NN - 1);   // PW has 100 rows; clamped rows discarded
            bf16x8 af = *(const bf16x8*)&PW[row * LDPW + ks * 32 + hi8];
            acc2[0][I] = __builtin_amdgcn_mfma_f32_16x16x32_bf16(af, dv0, acc2[0][I], 0, 0, 0);
            acc2[1][I] = __builtin_amdgcn_mfma_f32_16x16x32_bf16(af, dv1, acc2[1][I], 0, 0, 0);
        }
    }

    // ---------------- Phase D: LayerNorm ----------------
    #pragma unroll
    for (int I = 0; I < 7; ++I) {
        #pragma unroll
        for (int r = 0; r < 4; ++r) {
            float a = acc2[0][I][r], e = acc2[1][I][r];
            float s1 = a + e, s2 = a * a + e * e;
            #pragma unroll
            for (int mk = 1; mk < 16; mk <<= 1) {
                s1 += __shfl_xor(s1, mk);
                s2 += __shfl_xor(s2, mk);
            }
            int n = I * 16 + g * 4 + r;
            if (ln16 == 0 && n < NN) {
                RP[w][n][0] = s1;
                RP[w][n][1] = s2;
            }
        }
    }
    __syncthreads();
    if (t < NN) {
        float S1 = 0.f, S2 = 0.f;
        #pragma unroll
        for (int wi = 0; wi < 8; ++wi) { S1 += RP[wi][t][0]; S2 += RP[wi][t][1]; }
        float mu  = S1 * (1.f / 256.f);
        float var = S2 * (1.f / 256.f) - mu * mu;
        RS[t][0] = mu;
        RS[t][1] = rsqrtf(fmaxf(var, 0.f) + 1e-5f);
    }
    __syncthreads();

    // normalize + transpose through LDS -> coalesced f32x4 stores (kills 2x write amplification)
    const float gm0 = gamma[cb], gm1 = gamma[cb + 128];
    const float bt0 = beta[cb],  bt1 = beta[cb + 128];
    float* ob = out + (size_t)b * NN * CC;
    #pragma unroll
    for (int I = 0; I < 7; ++I) {
        #pragma unroll
        for (int r = 0; r < 4; ++r) {
            int n = I * 16 + g * 4 + r;
            if (n < NN) {
                float mu = RS[n][0], rs = RS[n][1];
                int rt = g * 4 + r;
                OT[rt * OTS + cb]       = (acc2[0][I][r] - mu) * rs * gm0 + bt0;
                OT[rt * OTS + cb + 128] = (acc2[1][I][r] - mu) * rs * gm1 + bt1;
            }
        }
        __syncthreads();
        #pragma unroll
        for (int p = 0; p < 2; ++p) {
            int idx  = p * 512 + t;          // 16 rows x 64 f32x4
            int row  = idx >> 6, c4 = (idx & 63) << 2;
            int grow = I * 16 + row;
            if (grow < NN)
                *(f32x4*)(ob + grow * CC + c4) = *(const f32x4*)&OT[row * OTS + c4];
        }
        __syncthreads();
    }
}

extern "C" void kernel_launch(void* const* d_in, const int* in_sizes, int n_in,
                              void* d_out, int out_size, void* d_ws, size_t ws_size,
                              hipStream_t stream) {
    const float* query = (const float*)d_in[0];
    const float* value = (const float*)d_in[1];
    const float* W     = (const float*)d_in[2];
    const float* bwl   = (const float*)d_in[3];
    const float* gamma = (const float*)d_in[4];
    const float* beta  = (const float*)d_in[5];
    dysepconv_fused<<<dim3(512), dim3(512), 0, stream>>>(query, value, W, bwl, gamma, beta, (float*)d_out);
}